// Round 4
// baseline (485.638 us; speedup 1.0000x reference)
//
#include <hip/hip_runtime.h>

#define NN 50000
#define NE 600000
#define NG 3
#define D  128
#define NI 4096
#define BW 1024                         // nodes per bucket
#define NBUCK 49                        // ceil(NN/BW)
#define EPT_BIN 16
#define EPB_BIN (256 * EPT_BIN)         // 4096 edges per block
#define NBLK_BIN ((NE + EPB_BIN - 1) / EPB_BIN)   // 147
#define UNR 8

// ---------------- CSR build, bucketed (write-amplification-free) ----------------

__global__ __launch_bounds__(256) void count_kernel(const int* __restrict__ e0,
    const int* __restrict__ e1, const int* __restrict__ e2, int* __restrict__ bucketCnt) {
  __shared__ int cnt[NBUCK];
  int g = blockIdx.y;
  const int* ei = (g == 0) ? e0 : ((g == 1) ? e1 : e2);
  int tid = threadIdx.x;
  if (tid < NBUCK) cnt[tid] = 0;
  __syncthreads();
  int base = blockIdx.x * EPB_BIN;
#pragma unroll
  for (int i = 0; i < EPT_BIN; i++) {
    int e = base + tid + i * 256;
    if (e < NE) atomicAdd(&cnt[ei[NE + e] >> 10], 1);
  }
  __syncthreads();
  if (tid < NBUCK) atomicAdd(&bucketCnt[g * NBUCK + tid], cnt[tid]);
}

__global__ void bscan_kernel(const int* __restrict__ bucketCnt, int* __restrict__ bucketBase,
                             int* __restrict__ cursor, int* __restrict__ rp) {
  int g = threadIdx.x;
  if (g >= NG) return;
  int run = 0;
  for (int b = 0; b < NBUCK; b++) {
    int c = bucketCnt[g * NBUCK + b];
    bucketBase[g * NBUCK + b] = run;
    cursor[g * NBUCK + b] = run;
    run += c;
  }
  rp[g * (NN + 1) + NN] = NE;
}

__global__ __launch_bounds__(256) void bin_kernel(const int* __restrict__ e0,
    const int* __restrict__ e1, const int* __restrict__ e2,
    int* __restrict__ cursor, int2* __restrict__ binned) {
  __shared__ int cnt[NBUCK];
  __shared__ int base[NBUCK];
  int g = blockIdx.y;
  const int* ei = (g == 0) ? e0 : ((g == 1) ? e1 : e2);
  int tid = threadIdx.x;
  if (tid < NBUCK) cnt[tid] = 0;
  __syncthreads();
  int estart = blockIdx.x * EPB_BIN;
  int src[EPT_BIN], dst[EPT_BIN], rk[EPT_BIN];
#pragma unroll
  for (int i = 0; i < EPT_BIN; i++) {
    int e = estart + tid + i * 256;
    if (e < NE) {
      src[i] = ei[e];
      dst[i] = ei[NE + e];
      rk[i] = atomicAdd(&cnt[dst[i] >> 10], 1);
    } else {
      rk[i] = -1;
    }
  }
  __syncthreads();
  if (tid < NBUCK) base[tid] = (cnt[tid] > 0) ? atomicAdd(&cursor[g * NBUCK + tid], cnt[tid]) : 0;
  __syncthreads();
#pragma unroll
  for (int i = 0; i < EPT_BIN; i++) {
    if (rk[i] >= 0) {
      int b = dst[i] >> 10;
      binned[(size_t)g * NE + base[b] + rk[i]] = make_int2(src[i], dst[i]);
    }
  }
}

__global__ __launch_bounds__(256) void csr_kernel(const int2* __restrict__ binned,
    const int* __restrict__ bucketBase, const int* __restrict__ bucketCnt,
    int* __restrict__ rp, int* __restrict__ col, float* __restrict__ dinv) {
  __shared__ int deg[BW];
  __shared__ int wsum[4];
  int g = blockIdx.y, b = blockIdx.x;
  int tid = threadIdx.x;
  int node0 = b * BW;
  int bb = bucketBase[g * NBUCK + b];
  int total = bucketCnt[g * NBUCK + b];
  const int2* bp = binned + (size_t)g * NE + bb;
  for (int i = tid; i < BW; i += 256) deg[i] = 0;
  __syncthreads();
  for (int e = tid; e < total; e += 256) {
    int2 p = bp[e];
    atomicAdd(&deg[p.y - node0], 1);
  }
  __syncthreads();
  int d0 = deg[tid * 4], d1 = deg[tid * 4 + 1], d2 = deg[tid * 4 + 2], d3 = deg[tid * 4 + 3];
  int s = d0 + d1 + d2 + d3;
  int lane = tid & 63;
  int incl = s;
#pragma unroll
  for (int off = 1; off < 64; off <<= 1) {
    int n = __shfl_up(incl, off, 64);
    if (lane >= off) incl += n;
  }
  if (lane == 63) wsum[tid >> 6] = incl;
  __syncthreads();
  int wbase = 0;
#pragma unroll
  for (int w = 0; w < 4; w++)
    if (w < (tid >> 6)) wbase += wsum[w];
  int ex = wbase + incl - s;
  int exs[4] = {ex, ex + d0, ex + d0 + d1, ex + d0 + d1 + d2};
  int ds[4] = {d0, d1, d2, d3};
#pragma unroll
  for (int k = 0; k < 4; k++) {
    int node = node0 + tid * 4 + k;
    if (node < NN) {
      rp[g * (NN + 1) + node] = bb + exs[k];
      dinv[g * NN + node] = rsqrtf((float)ds[k] + 1.0f);
    }
    deg[tid * 4 + k] = exs[k];
  }
  __syncthreads();
  for (int e = tid; e < total; e += 256) {
    int2 p = bp[e];
    int r = atomicAdd(&deg[p.y - node0], 1);
    col[(size_t)g * NE + bb + r] = p.x;
  }
}

// ---------------- fused 3-branch aggregation ----------------
// tout[b][w] = dinv_b[i]*( dinv_b[i]*src[i] + sum_{e in graph b} dinv_b[s]*src[s] ),
// i = index ? index[w] : w.  Three branches interleaved for memory-level parallelism.

__global__ __launch_bounds__(256) void aggf_kernel(
    const float* __restrict__ src, const int* __restrict__ rp,
    const int* __restrict__ col, const float* __restrict__ dinv,
    const int* __restrict__ index, float* __restrict__ tout, int nrows) {
  int w = (blockIdx.x * 256 + threadIdx.x) >> 6;
  if (w >= nrows) return;
  int lane = threadIdx.x & 63;
  int node = index ? index[w] : w;
  int d0 = lane * 2;
  float2 self = *(const float2*)&src[(size_t)node * D + d0];
  float di0 = dinv[node];
  float di1 = dinv[NN + node];
  float di2 = dinv[2 * NN + node];
  int s0 = rp[node],               e0 = rp[node + 1];
  int s1 = rp[(NN + 1) + node],    e1 = rp[(NN + 1) + node + 1];
  int s2 = rp[2 * (NN + 1) + node], e2 = rp[2 * (NN + 1) + node + 1];
  int n0 = e0 - s0, n1 = e1 - s1, n2 = e2 - s2;
  int c0 = (lane < n0) ? col[s0 + lane] : 0;
  int c1 = (lane < n1) ? col[NE + s1 + lane] : 0;
  int c2 = (lane < n2) ? col[2 * NE + s2 + lane] : 0;
  float ax0 = di0 * self.x, ay0 = di0 * self.y;
  float ax1 = di1 * self.x, ay1 = di1 * self.y;
  float ax2 = di2 * self.x, ay2 = di2 * self.y;
  int m0 = min(n0, 64), m1 = min(n1, 64), m2 = min(n2, 64);
  int mx = max(m0, max(m1, m2));
  for (int j = 0; j < mx; j += UNR) {
    float2 v0[UNR], v1[UNR], v2[UNR];
    float g0[UNR], g1[UNR], g2[UNR];
#pragma unroll
    for (int k = 0; k < UNR; k++) {
      int jk = j + k;
      int t0 = __shfl(c0, jk, 64); t0 = (jk < m0) ? t0 : node;
      int t1 = __shfl(c1, jk, 64); t1 = (jk < m1) ? t1 : node;
      int t2 = __shfl(c2, jk, 64); t2 = (jk < m2) ? t2 : node;
      g0[k] = (jk < m0) ? dinv[t0] : 0.f;
      g1[k] = (jk < m1) ? dinv[NN + t1] : 0.f;
      g2[k] = (jk < m2) ? dinv[2 * NN + t2] : 0.f;
      v0[k] = *(const float2*)&src[(size_t)t0 * D + d0];
      v1[k] = *(const float2*)&src[(size_t)t1 * D + d0];
      v2[k] = *(const float2*)&src[(size_t)t2 * D + d0];
    }
#pragma unroll
    for (int k = 0; k < UNR; k++) {
      ax0 += g0[k] * v0[k].x; ay0 += g0[k] * v0[k].y;
      ax1 += g1[k] * v1[k].x; ay1 += g1[k] * v1[k].y;
      ax2 += g2[k] * v2[k].x; ay2 += g2[k] * v2[k].y;
    }
  }
  // rare tails (deg > 64), wave-uniform branches
  for (int q = s0 + 64; q < e0; q += 64) {
    int nn = min(e0 - q, 64);
    int c = (lane < nn) ? col[q + lane] : 0;
    for (int j = 0; j < nn; j++) {
      int t = __shfl(c, j, 64);
      float g = dinv[t];
      float2 v = *(const float2*)&src[(size_t)t * D + d0];
      ax0 += g * v.x; ay0 += g * v.y;
    }
  }
  for (int q = s1 + 64; q < e1; q += 64) {
    int nn = min(e1 - q, 64);
    int c = (lane < nn) ? col[NE + q + lane] : 0;
    for (int j = 0; j < nn; j++) {
      int t = __shfl(c, j, 64);
      float g = dinv[NN + t];
      float2 v = *(const float2*)&src[(size_t)t * D + d0];
      ax1 += g * v.x; ay1 += g * v.y;
    }
  }
  for (int q = s2 + 64; q < e2; q += 64) {
    int nn = min(e2 - q, 64);
    int c = (lane < nn) ? col[2 * NE + q + lane] : 0;
    for (int j = 0; j < nn; j++) {
      int t = __shfl(c, j, 64);
      float g = dinv[2 * NN + t];
      float2 v = *(const float2*)&src[(size_t)t * D + d0];
      ax2 += g * v.x; ay2 += g * v.y;
    }
  }
  size_t stride = (size_t)nrows * D;
  *(float2*)&tout[(size_t)w * D + d0]              = make_float2(di0 * ax0, di0 * ay0);
  *(float2*)&tout[stride + (size_t)w * D + d0]     = make_float2(di1 * ax1, di1 * ay1);
  *(float2*)&tout[2 * stride + (size_t)w * D + d0] = make_float2(di2 * ax2, di2 * ay2);
}

// ---------------- fused 3-branch matmul + bias + relu + max ----------------
// O[r] = max_b relu( A_b[r] @ W_b + bias_b ),  A_b = A + b*M*D

__global__ __launch_bounds__(256) void mmf_kernel(const float* __restrict__ A,
    const float* __restrict__ W0, const float* __restrict__ W1, const float* __restrict__ W2,
    const float* __restrict__ B0, const float* __restrict__ B1, const float* __restrict__ B2,
    float* __restrict__ O, int M) {
  __shared__ float As[64][68];
  __shared__ float Ws[64][132];
  const float* Wb[3] = {W0, W1, W2};
  const float* Bb[3] = {B0, B1, B2};
  const int tid = threadIdx.x;
  const int tx = tid & 15, ty = tid >> 4;
  const int row0 = blockIdx.x * 64;
  const int c0 = tx * 8;
  float om[4][8];

  for (int b = 0; b < 3; b++) {
    const float* Ab = A + (size_t)b * M * D;
    const float* Wp = Wb[b];
    float acc[4][8];
#pragma unroll
    for (int r = 0; r < 4; r++)
#pragma unroll
      for (int c = 0; c < 8; c++) acc[r][c] = 0.f;

    for (int kc = 0; kc < 128; kc += 64) {
#pragma unroll
      for (int t = 0; t < 4; ++t) {
        int idx = tid + t * 256;
        int r = idx >> 4;
        int cc = (idx & 15) * 4;
        float4 v = make_float4(0.f, 0.f, 0.f, 0.f);
        int gr = row0 + r;
        if (gr < M) v = *(const float4*)&Ab[(size_t)gr * 128 + kc + cc];
        *(float4*)&As[r][cc] = v;
      }
#pragma unroll
      for (int t = 0; t < 8; ++t) {
        int idx = tid + t * 256;
        int k = idx >> 5;
        int cc = (idx & 31) * 4;
        float4 v = *(const float4*)&Wp[(size_t)(kc + k) * 128 + cc];
        *(float4*)&Ws[k][cc] = v;
      }
      __syncthreads();
#pragma unroll
      for (int k4 = 0; k4 < 16; ++k4) {
        float4 a4[4];
#pragma unroll
        for (int r = 0; r < 4; r++) a4[r] = *(const float4*)&As[ty + r * 16][k4 * 4];
#pragma unroll
        for (int kk = 0; kk < 4; kk++) {
          float4 w0 = *(const float4*)&Ws[k4 * 4 + kk][c0];
          float4 w1 = *(const float4*)&Ws[k4 * 4 + kk][c0 + 4];
#pragma unroll
          for (int r = 0; r < 4; r++) {
            float a = (&a4[r].x)[kk];
            acc[r][0] += a * w0.x; acc[r][1] += a * w0.y;
            acc[r][2] += a * w0.z; acc[r][3] += a * w0.w;
            acc[r][4] += a * w1.x; acc[r][5] += a * w1.y;
            acc[r][6] += a * w1.z; acc[r][7] += a * w1.w;
          }
        }
      }
      __syncthreads();
    }
    float bias[8];
#pragma unroll
    for (int c = 0; c < 8; c++) bias[c] = Bb[b][c0 + c];
#pragma unroll
    for (int r = 0; r < 4; r++)
#pragma unroll
      for (int c = 0; c < 8; c++) {
        float v = fmaxf(acc[r][c] + bias[c], 0.f);
        om[r][c] = (b == 0) ? v : fmaxf(om[r][c], v);
      }
  }
#pragma unroll
  for (int r = 0; r < 4; r++) {
    int gr = row0 + ty + r * 16;
    if (gr < M) {
      *(float4*)&O[(size_t)gr * 128 + c0] =
          make_float4(om[r][0], om[r][1], om[r][2], om[r][3]);
      *(float4*)&O[(size_t)gr * 128 + c0 + 4] =
          make_float4(om[r][4], om[r][5], om[r][6], om[r][7]);
    }
  }
}

// ---------------- launch ----------------

extern "C" void kernel_launch(void* const* d_in, const int* in_sizes, int n_in,
                              void* d_out, int out_size, void* d_ws, size_t ws_size,
                              hipStream_t stream) {
  const float* x = (const float*)d_in[0];
  const int* e0 = (const int*)d_in[1];
  const int* e1 = (const int*)d_in[2];
  const int* e2 = (const int*)d_in[3];
  const int* index = (const int*)d_in[4];
  const float* w1[3] = {(const float*)d_in[5], (const float*)d_in[9],  (const float*)d_in[13]};
  const float* b1[3] = {(const float*)d_in[6], (const float*)d_in[10], (const float*)d_in[14]};
  const float* w2[3] = {(const float*)d_in[7], (const float*)d_in[11], (const float*)d_in[15]};
  const float* b2[3] = {(const float*)d_in[8], (const float*)d_in[12], (const float*)d_in[16]};
  float* out = (float*)d_out;

  char* ws = (char*)d_ws;
  size_t o = 0;
  auto alloc = [&](size_t bytes) {
    o = (o + 255) & ~(size_t)255;
    void* p = ws + o;
    o += bytes;
    return p;
  };
  int*   rp     = (int*)alloc((size_t)NG * (NN + 1) * 4);
  int*   col    = (int*)alloc((size_t)NG * NE * 4);
  float* dinv   = (float*)alloc((size_t)NG * NN * 4);
  int*   bcnt   = (int*)alloc((size_t)NG * NBUCK * 4);
  int*   bbase  = (int*)alloc((size_t)NG * NBUCK * 4);
  int*   bcur   = (int*)alloc((size_t)NG * NBUCK * 4);
  float* t1     = (float*)alloc((size_t)NG * NN * D * 4);   // 76.8 MB
  float* hacc   = (float*)alloc((size_t)NN * D * 4);        // 25.6 MB
  int2*  binned = (int2*)t1;   // alias: consumed by csr_kernel before aggf writes t1
  float* t2     = t1;          // alias: t1 free during layer 2
  (void)ws_size; (void)in_sizes; (void)n_in; (void)out_size;

  hipMemsetAsync(bcnt, 0, (size_t)NG * NBUCK * 4, stream);
  count_kernel<<<dim3(NBLK_BIN, NG), 256, 0, stream>>>(e0, e1, e2, bcnt);
  bscan_kernel<<<1, 64, 0, stream>>>(bcnt, bbase, bcur, rp);
  bin_kernel<<<dim3(NBLK_BIN, NG), 256, 0, stream>>>(e0, e1, e2, bcur, binned);
  csr_kernel<<<dim3(NBUCK, NG), 256, 0, stream>>>(binned, bbase, bcnt, rp, col, dinv);

  // layer 1: t1_b = Norm_b(x);  hacc = max_b relu(t1_b @ W1_b + b1_b)
  aggf_kernel<<<(NN * 64 + 255) / 256, 256, 0, stream>>>(x, rp, col, dinv, nullptr, t1, NN);
  mmf_kernel<<<(NN + 63) / 64, 256, 0, stream>>>(t1, w1[0], w1[1], w1[2],
                                                 b1[0], b1[1], b1[2], hacc, NN);
  // layer 2: t2_b = Norm_b(hacc)[index];  out = max_b relu(t2_b @ W2_b + b2_b)
  aggf_kernel<<<(NI * 64 + 255) / 256, 256, 0, stream>>>(hacc, rp, col, dinv, index, t2, NI);
  mmf_kernel<<<(NI + 63) / 64, 256, 0, stream>>>(t2, w2[0], w2[1], w2[2],
                                                 b2[0], b2[1], b2[2], out, NI);
}

// Round 5
// 312.165 us; speedup vs baseline: 1.5557x; 1.5557x over previous
//
#include <hip/hip_runtime.h>
#include <hip/hip_fp16.h>

#define NN 50000
#define NE 600000
#define NG 3
#define D  128
#define NI 4096
#define BW 1024                         // nodes per bucket
#define NBUCK 49                        // ceil(NN/BW)
#define EPT_BIN 16
#define EPB_BIN (256 * EPT_BIN)         // 4096 edges per block
#define NBLK_BIN ((NE + EPB_BIN - 1) / EPB_BIN)   // 147
#define UNR 8

typedef _Float16 half8 __attribute__((ext_vector_type(8)));
typedef float floatx4 __attribute__((ext_vector_type(4)));

// ---------------- dtype conversion ----------------

__global__ __launch_bounds__(256) void xcvt_kernel(const float* __restrict__ x,
    __half* __restrict__ xh, int n2) {
  int i = blockIdx.x * 256 + threadIdx.x;
  if (i >= n2) return;
  float2 v = ((const float2*)x)[i];
  ((__half2*)xh)[i] = __floats2half2_rn(v.x, v.y);
}

// weights -> fp16, fragment-order: Wf[mat][frag][lane][j], frag=(tt*4+ks),
// element = W[mat][k = ks*32 + (lane>>4)*8 + j][n = tt*16 + (lane&15)]
__global__ __launch_bounds__(256) void wcvt_kernel(
    const float* __restrict__ W0, const float* __restrict__ W1, const float* __restrict__ W2,
    const float* __restrict__ W3, const float* __restrict__ W4, const float* __restrict__ W5,
    __half* __restrict__ Wf) {
  const float* Wm[6] = {W0, W1, W2, W3, W4, W5};
  int t = blockIdx.x * 256 + threadIdx.x;        // 0 .. 6*2048-1
  if (t >= 6 * 2048) return;
  int mat = t >> 11;
  int fr = (t >> 6) & 31;
  int lane = t & 63;
  int tt = fr >> 2, ks = fr & 3;
  int n = tt * 16 + (lane & 15);
  int kb = ks * 32 + (lane >> 4) * 8;
  const float* W = Wm[mat];
#pragma unroll
  for (int j = 0; j < 8; j++)
    Wf[(size_t)t * 8 + j] = __float2half(W[(kb + j) * 128 + n]);
}

// ---------------- CSR build, bucketed + packed edges ----------------

__global__ __launch_bounds__(256) void count_kernel(const int* __restrict__ e0,
    const int* __restrict__ e1, const int* __restrict__ e2, int* __restrict__ bucketCnt) {
  __shared__ int cnt[NBUCK];
  int g = blockIdx.y;
  const int* ei = (g == 0) ? e0 : ((g == 1) ? e1 : e2);
  int tid = threadIdx.x;
  if (tid < NBUCK) cnt[tid] = 0;
  __syncthreads();
  int base = blockIdx.x * EPB_BIN;
#pragma unroll
  for (int i = 0; i < EPT_BIN; i++) {
    int e = base + tid + i * 256;
    if (e < NE) atomicAdd(&cnt[ei[NE + e] >> 10], 1);
  }
  __syncthreads();
  if (tid < NBUCK) atomicAdd(&bucketCnt[g * NBUCK + tid], cnt[tid]);
}

__global__ void bscan_kernel(const int* __restrict__ bucketCnt, int* __restrict__ bucketBase,
                             int* __restrict__ cursor, int* __restrict__ rp) {
  int g = threadIdx.x;
  if (g >= NG) return;
  int run = 0;
  for (int b = 0; b < NBUCK; b++) {
    int c = bucketCnt[g * NBUCK + b];
    bucketBase[g * NBUCK + b] = run;
    cursor[g * NBUCK + b] = run;
    run += c;
  }
  rp[g * (NN + 1) + NN] = NE;
}

__global__ __launch_bounds__(256) void bin_kernel(const int* __restrict__ e0,
    const int* __restrict__ e1, const int* __restrict__ e2,
    int* __restrict__ cursor, unsigned int* __restrict__ binned) {
  __shared__ int cnt[NBUCK];
  __shared__ int base[NBUCK];
  int g = blockIdx.y;
  const int* ei = (g == 0) ? e0 : ((g == 1) ? e1 : e2);
  int tid = threadIdx.x;
  if (tid < NBUCK) cnt[tid] = 0;
  __syncthreads();
  int estart = blockIdx.x * EPB_BIN;
  int src[EPT_BIN], dst[EPT_BIN], rk[EPT_BIN];
#pragma unroll
  for (int i = 0; i < EPT_BIN; i++) {
    int e = estart + tid + i * 256;
    if (e < NE) {
      src[i] = ei[e];
      dst[i] = ei[NE + e];
      rk[i] = atomicAdd(&cnt[dst[i] >> 10], 1);
    } else {
      rk[i] = -1;
    }
  }
  __syncthreads();
  if (tid < NBUCK) base[tid] = (cnt[tid] > 0) ? atomicAdd(&cursor[g * NBUCK + tid], cnt[tid]) : 0;
  __syncthreads();
#pragma unroll
  for (int i = 0; i < EPT_BIN; i++) {
    if (rk[i] >= 0) {
      int b = dst[i] >> 10;
      binned[(size_t)g * NE + base[b] + rk[i]] =
          (unsigned int)src[i] | ((unsigned int)dst[i] << 16);
    }
  }
}

__global__ __launch_bounds__(256) void csr_kernel(const unsigned int* __restrict__ binned,
    const int* __restrict__ bucketBase, const int* __restrict__ bucketCnt,
    int* __restrict__ rp, int* __restrict__ col, float* __restrict__ dinv) {
  __shared__ int deg[BW];
  __shared__ int wsum[4];
  int g = blockIdx.y, b = blockIdx.x;
  int tid = threadIdx.x;
  int node0 = b * BW;
  int bb = bucketBase[g * NBUCK + b];
  int total = bucketCnt[g * NBUCK + b];
  const unsigned int* bp = binned + (size_t)g * NE + bb;
  for (int i = tid; i < BW; i += 256) deg[i] = 0;
  __syncthreads();
  for (int e = tid; e < total; e += 256) {
    unsigned int p = bp[e];
    atomicAdd(&deg[(int)(p >> 16) - node0], 1);
  }
  __syncthreads();
  int d0 = deg[tid * 4], d1 = deg[tid * 4 + 1], d2 = deg[tid * 4 + 2], d3 = deg[tid * 4 + 3];
  int s = d0 + d1 + d2 + d3;
  int lane = tid & 63;
  int incl = s;
#pragma unroll
  for (int off = 1; off < 64; off <<= 1) {
    int n = __shfl_up(incl, off, 64);
    if (lane >= off) incl += n;
  }
  if (lane == 63) wsum[tid >> 6] = incl;
  __syncthreads();
  int wbase = 0;
#pragma unroll
  for (int w = 0; w < 4; w++)
    if (w < (tid >> 6)) wbase += wsum[w];
  int ex = wbase + incl - s;
  int exs[4] = {ex, ex + d0, ex + d0 + d1, ex + d0 + d1 + d2};
  int ds[4] = {d0, d1, d2, d3};
#pragma unroll
  for (int k = 0; k < 4; k++) {
    int node = node0 + tid * 4 + k;
    if (node < NN) {
      rp[g * (NN + 1) + node] = bb + exs[k];
      dinv[g * NN + node] = rsqrtf((float)ds[k] + 1.0f);
    }
    deg[tid * 4 + k] = exs[k];
  }
  __syncthreads();
  for (int e = tid; e < total; e += 256) {
    unsigned int p = bp[e];
    int r = atomicAdd(&deg[(int)(p >> 16) - node0], 1);
    col[(size_t)g * NE + bb + r] = (int)(p & 0xffffu);
  }
}

// ---------------- fused 3-branch aggregation (fp16 rows, fp32 accumulate) ----------------

__global__ __launch_bounds__(256) void aggf_kernel(
    const __half* __restrict__ src, const int* __restrict__ rp,
    const int* __restrict__ col, const float* __restrict__ dinv,
    const int* __restrict__ index, __half* __restrict__ tout, int nrows) {
  int w = (blockIdx.x * 256 + threadIdx.x) >> 6;
  if (w >= nrows) return;
  int lane = threadIdx.x & 63;
  int node = index ? index[w] : w;
  int d0 = lane * 2;
  float2 self = __half22float2(*(const __half2*)&src[(size_t)node * D + d0]);
  float di0 = dinv[node];
  float di1 = dinv[NN + node];
  float di2 = dinv[2 * NN + node];
  int s0 = rp[node],                e0 = rp[node + 1];
  int s1 = rp[(NN + 1) + node],     e1 = rp[(NN + 1) + node + 1];
  int s2 = rp[2 * (NN + 1) + node], e2 = rp[2 * (NN + 1) + node + 1];
  int n0 = e0 - s0, n1 = e1 - s1, n2 = e2 - s2;
  int c0 = (lane < n0) ? col[s0 + lane] : 0;
  int c1 = (lane < n1) ? col[NE + s1 + lane] : 0;
  int c2 = (lane < n2) ? col[2 * NE + s2 + lane] : 0;
  float ax0 = di0 * self.x, ay0 = di0 * self.y;
  float ax1 = di1 * self.x, ay1 = di1 * self.y;
  float ax2 = di2 * self.x, ay2 = di2 * self.y;
  int m0 = min(n0, 64), m1 = min(n1, 64), m2 = min(n2, 64);
  int mx = max(m0, max(m1, m2));
  for (int j = 0; j < mx; j += UNR) {
    float2 v0[UNR], v1[UNR], v2[UNR];
    float g0[UNR], g1[UNR], g2[UNR];
#pragma unroll
    for (int k = 0; k < UNR; k++) {
      int jk = j + k;
      int t0 = __shfl(c0, jk, 64); t0 = (jk < m0) ? t0 : node;
      int t1 = __shfl(c1, jk, 64); t1 = (jk < m1) ? t1 : node;
      int t2 = __shfl(c2, jk, 64); t2 = (jk < m2) ? t2 : node;
      g0[k] = (jk < m0) ? dinv[t0] : 0.f;
      g1[k] = (jk < m1) ? dinv[NN + t1] : 0.f;
      g2[k] = (jk < m2) ? dinv[2 * NN + t2] : 0.f;
      v0[k] = __half22float2(*(const __half2*)&src[(size_t)t0 * D + d0]);
      v1[k] = __half22float2(*(const __half2*)&src[(size_t)t1 * D + d0]);
      v2[k] = __half22float2(*(const __half2*)&src[(size_t)t2 * D + d0]);
    }
#pragma unroll
    for (int k = 0; k < UNR; k++) {
      ax0 += g0[k] * v0[k].x; ay0 += g0[k] * v0[k].y;
      ax1 += g1[k] * v1[k].x; ay1 += g1[k] * v1[k].y;
      ax2 += g2[k] * v2[k].x; ay2 += g2[k] * v2[k].y;
    }
  }
  // rare tails (deg > 64)
  for (int q = s0 + 64; q < e0; q += 64) {
    int nn = min(e0 - q, 64);
    int c = (lane < nn) ? col[q + lane] : 0;
    for (int j = 0; j < nn; j++) {
      int t = __shfl(c, j, 64);
      float g = dinv[t];
      float2 v = __half22float2(*(const __half2*)&src[(size_t)t * D + d0]);
      ax0 += g * v.x; ay0 += g * v.y;
    }
  }
  for (int q = s1 + 64; q < e1; q += 64) {
    int nn = min(e1 - q, 64);
    int c = (lane < nn) ? col[NE + q + lane] : 0;
    for (int j = 0; j < nn; j++) {
      int t = __shfl(c, j, 64);
      float g = dinv[NN + t];
      float2 v = __half22float2(*(const __half2*)&src[(size_t)t * D + d0]);
      ax1 += g * v.x; ay1 += g * v.y;
    }
  }
  for (int q = s2 + 64; q < e2; q += 64) {
    int nn = min(e2 - q, 64);
    int c = (lane < nn) ? col[2 * NE + q + lane] : 0;
    for (int j = 0; j < nn; j++) {
      int t = __shfl(c, j, 64);
      float g = dinv[2 * NN + t];
      float2 v = __half22float2(*(const __half2*)&src[(size_t)t * D + d0]);
      ax2 += g * v.x; ay2 += g * v.y;
    }
  }
  size_t stride = (size_t)nrows * D;
  *(__half2*)&tout[(size_t)w * D + d0]              = __floats2half2_rn(di0 * ax0, di0 * ay0);
  *(__half2*)&tout[stride + (size_t)w * D + d0]     = __floats2half2_rn(di1 * ax1, di1 * ay1);
  *(__half2*)&tout[2 * stride + (size_t)w * D + d0] = __floats2half2_rn(di2 * ax2, di2 * ay2);
}

// ---------------- fused 3-branch MFMA fp16 matmul + bias + relu + max ----------------
// O[m] = max_b relu( A_b[m] @ W_b + bias_b ).  A: [3][M][128] fp16.
// Wf: fragment-order fp16 (see wcvt). Block: 128 rows x 128 cols, 4 waves in 2x2.

__global__ __launch_bounds__(256) void mmf_kernel(const __half* __restrict__ A,
    const __half* __restrict__ Wf,
    const float* __restrict__ B0, const float* __restrict__ B1, const float* __restrict__ B2,
    __half* __restrict__ outh, float* __restrict__ outf, int M) {
  __shared__ _Float16 Ws[16384];      // 32 frags x 64 lanes x 8 halves = 32 KB
  const float* Bb[3] = {B0, B1, B2};
  const int tid = threadIdx.x;
  const int wave = tid >> 6, lane = tid & 63;
  const int wr = (wave >> 1) * 64, wc = (wave & 1) * 64;
  const int ln = lane & 15, quad = lane >> 4;
  const int row_base = blockIdx.x * 128 + wr;
  float om[4][4][4];

  for (int b = 0; b < 3; b++) {
    const __half* Wb = Wf + (size_t)b * 16384;
#pragma unroll
    for (int i = 0; i < 8; i++) {
      int id = tid + i * 256;
      *(half8*)&Ws[id * 8] = *(const half8*)&Wb[(size_t)id * 8];
    }
    __syncthreads();

    const __half* Ab = A + (size_t)b * M * D;
    float bias[4];
#pragma unroll
    for (int ct = 0; ct < 4; ct++) bias[ct] = Bb[b][wc + ct * 16 + ln];
    floatx4 acc[4][4];
#pragma unroll
    for (int rt = 0; rt < 4; rt++)
#pragma unroll
      for (int ct = 0; ct < 4; ct++)
        acc[rt][ct] = (floatx4){bias[ct], bias[ct], bias[ct], bias[ct]};

#pragma unroll
    for (int ks = 0; ks < 4; ks++) {
      half8 av[4];
#pragma unroll
      for (int rt = 0; rt < 4; rt++) {
        int r = row_base + rt * 16 + ln;
        r = (r < M) ? r : (M - 1);
        av[rt] = *(const half8*)&Ab[(size_t)r * D + ks * 32 + quad * 8];
      }
#pragma unroll
      for (int ct = 0; ct < 4; ct++) {
        int tt = (wc >> 4) + ct;
        half8 bv = *(const half8*)&Ws[((tt * 4 + ks) * 64 + lane) * 8];
#pragma unroll
        for (int rt = 0; rt < 4; rt++)
          acc[rt][ct] = __builtin_amdgcn_mfma_f32_16x16x32_f16(av[rt], bv, acc[rt][ct], 0, 0, 0);
      }
    }
#pragma unroll
    for (int rt = 0; rt < 4; rt++)
#pragma unroll
      for (int ct = 0; ct < 4; ct++)
#pragma unroll
        for (int r = 0; r < 4; r++) {
          float v = fmaxf(acc[rt][ct][r], 0.f);
          om[rt][ct][r] = (b == 0) ? v : fmaxf(om[rt][ct][r], v);
        }
    __syncthreads();
  }
#pragma unroll
  for (int rt = 0; rt < 4; rt++) {
    int m = row_base + rt * 16 + quad * 4;
#pragma unroll
    for (int r = 0; r < 4; r++) {
      if (m + r < M) {
#pragma unroll
        for (int ct = 0; ct < 4; ct++) {
          int n = wc + ct * 16 + ln;
          if (outh) outh[(size_t)(m + r) * D + n] = __float2half(om[rt][ct][r]);
          else      outf[(size_t)(m + r) * D + n] = om[rt][ct][r];
        }
      }
    }
  }
}

// ---------------- launch ----------------

extern "C" void kernel_launch(void* const* d_in, const int* in_sizes, int n_in,
                              void* d_out, int out_size, void* d_ws, size_t ws_size,
                              hipStream_t stream) {
  const float* x = (const float*)d_in[0];
  const int* e0 = (const int*)d_in[1];
  const int* e1 = (const int*)d_in[2];
  const int* e2 = (const int*)d_in[3];
  const int* index = (const int*)d_in[4];
  const float* w1[3] = {(const float*)d_in[5], (const float*)d_in[9],  (const float*)d_in[13]};
  const float* b1[3] = {(const float*)d_in[6], (const float*)d_in[10], (const float*)d_in[14]};
  const float* w2[3] = {(const float*)d_in[7], (const float*)d_in[11], (const float*)d_in[15]};
  const float* b2[3] = {(const float*)d_in[8], (const float*)d_in[12], (const float*)d_in[16]};
  float* out = (float*)d_out;

  char* ws = (char*)d_ws;
  size_t o = 0;
  auto alloc = [&](size_t bytes) {
    o = (o + 255) & ~(size_t)255;
    void* p = ws + o;
    o += bytes;
    return p;
  };
  int*    rp     = (int*)alloc((size_t)NG * (NN + 1) * 4);
  int*    col    = (int*)alloc((size_t)NG * NE * 4);
  float*  dinv   = (float*)alloc((size_t)NG * NN * 4);
  int*    bcnt   = (int*)alloc((size_t)NG * NBUCK * 4);
  int*    bbase  = (int*)alloc((size_t)NG * NBUCK * 4);
  int*    bcur   = (int*)alloc((size_t)NG * NBUCK * 4);
  __half* xh     = (__half*)alloc((size_t)NN * D * 2);        // 12.8 MB
  __half* Wf     = (__half*)alloc((size_t)6 * 128 * 128 * 2); // 196 KB
  __half* t1     = (__half*)alloc((size_t)NG * NN * D * 2);   // 38.4 MB
  __half* hacc   = (__half*)alloc((size_t)NN * D * 2);        // 12.8 MB
  unsigned int* binned = (unsigned int*)t1;  // alias: consumed by csr before aggf writes t1
  __half* t2     = t1;                       // alias: t1 free during layer 2
  (void)ws_size; (void)in_sizes; (void)n_in; (void)out_size;

  hipMemsetAsync(bcnt, 0, (size_t)NG * NBUCK * 4, stream);
  xcvt_kernel<<<(NN * D / 2 + 255) / 256, 256, 0, stream>>>(x, xh, NN * D / 2);
  wcvt_kernel<<<48, 256, 0, stream>>>(w1[0], w1[1], w1[2], w2[0], w2[1], w2[2], Wf);
  count_kernel<<<dim3(NBLK_BIN, NG), 256, 0, stream>>>(e0, e1, e2, bcnt);
  bscan_kernel<<<1, 64, 0, stream>>>(bcnt, bbase, bcur, rp);
  bin_kernel<<<dim3(NBLK_BIN, NG), 256, 0, stream>>>(e0, e1, e2, bcur, binned);
  csr_kernel<<<dim3(NBUCK, NG), 256, 0, stream>>>(binned, bbase, bcnt, rp, col, dinv);

  // layer 1: t1_b = Norm_b(xh);  hacc = max_b relu(t1_b @ W1_b + b1_b)   [fp16]
  aggf_kernel<<<(NN * 64 + 255) / 256, 256, 0, stream>>>(xh, rp, col, dinv, nullptr, t1, NN);
  mmf_kernel<<<(NN + 127) / 128, 256, 0, stream>>>(t1, Wf, b1[0], b1[1], b1[2],
                                                   hacc, nullptr, NN);
  // layer 2: t2_b = Norm_b(hacc)[index];  out = max_b relu(t2_b @ W2_b + b2_b)
  aggf_kernel<<<(NI * 64 + 255) / 256, 256, 0, stream>>>(hacc, rp, col, dinv, index, t2, NI);
  mmf_kernel<<<(NI + 127) / 128, 256, 0, stream>>>(t2, Wf + (size_t)3 * 16384,
                                                   b2[0], b2[1], b2[2], nullptr, out, NI);
}

// Round 6
// 297.499 us; speedup vs baseline: 1.6324x; 1.0493x over previous
//
#include <hip/hip_runtime.h>
#include <hip/hip_fp16.h>

#define NN 50000
#define NE 600000
#define NG 3
#define D  128
#define NI 4096
#define BW 1024                         // nodes per bucket
#define NBUCK 49                        // ceil(NN/BW)
#define EPT_BIN 16
#define EPB_BIN (256 * EPT_BIN)         // 4096 edges per block
#define NBLK_BIN ((NE + EPB_BIN - 1) / EPB_BIN)   // 147

typedef _Float16 half8 __attribute__((ext_vector_type(8)));
typedef _Float16 half4v __attribute__((ext_vector_type(4)));
typedef float floatx4 __attribute__((ext_vector_type(4)));

static __device__ __forceinline__ float wextract(unsigned int v) {
  unsigned short u = (unsigned short)(v >> 16);
  _Float16 h;
  __builtin_memcpy(&h, &u, 2);
  return (float)h;
}

static __device__ __forceinline__ unsigned int packsw(int s, float w) {
  _Float16 h = (_Float16)w;
  unsigned short u;
  __builtin_memcpy(&u, &h, 2);
  return (unsigned int)s | ((unsigned int)u << 16);
}

// ---------------- dtype conversion ----------------

__global__ __launch_bounds__(256) void xcvt_kernel(const float* __restrict__ x,
    __half* __restrict__ xh, int n2) {
  int i = blockIdx.x * 256 + threadIdx.x;
  if (i >= n2) return;
  float2 v = ((const float2*)x)[i];
  ((__half2*)xh)[i] = __floats2half2_rn(v.x, v.y);
}

// weights -> fp16, fragment-order: Wf[mat][frag][lane][j], frag=(tt*4+ks),
// element = W[mat][k = ks*32 + (lane>>4)*8 + j][n = tt*16 + (lane&15)]
__global__ __launch_bounds__(256) void wcvt_kernel(
    const float* __restrict__ W0, const float* __restrict__ W1, const float* __restrict__ W2,
    const float* __restrict__ W3, const float* __restrict__ W4, const float* __restrict__ W5,
    __half* __restrict__ Wf) {
  const float* Wm[6] = {W0, W1, W2, W3, W4, W5};
  int t = blockIdx.x * 256 + threadIdx.x;        // 0 .. 6*2048-1
  if (t >= 6 * 2048) return;
  int mat = t >> 11;
  int fr = (t >> 6) & 31;
  int lane = t & 63;
  int tt = fr >> 2, ks = fr & 3;
  int n = tt * 16 + (lane & 15);
  int kb = ks * 32 + (lane >> 4) * 8;
  const float* W = Wm[mat];
#pragma unroll
  for (int j = 0; j < 8; j++)
    Wf[(size_t)t * 8 + j] = __float2half(W[(kb + j) * 128 + n]);
}

// ---------------- CSR build, bucketed + packed (src | fp16 weight) ----------------

__global__ __launch_bounds__(256) void count_kernel(const int* __restrict__ e0,
    const int* __restrict__ e1, const int* __restrict__ e2, int* __restrict__ bucketCnt) {
  __shared__ int cnt[NBUCK];
  int g = blockIdx.y;
  const int* ei = (g == 0) ? e0 : ((g == 1) ? e1 : e2);
  int tid = threadIdx.x;
  if (tid < NBUCK) cnt[tid] = 0;
  __syncthreads();
  int base = blockIdx.x * EPB_BIN;
#pragma unroll
  for (int i = 0; i < EPT_BIN; i++) {
    int e = base + tid + i * 256;
    if (e < NE) atomicAdd(&cnt[ei[NE + e] >> 10], 1);
  }
  __syncthreads();
  if (tid < NBUCK) atomicAdd(&bucketCnt[g * NBUCK + tid], cnt[tid]);
}

__global__ void bscan_kernel(const int* __restrict__ bucketCnt, int* __restrict__ bucketBase,
                             int* __restrict__ cursor, int* __restrict__ rp) {
  int g = threadIdx.x;
  if (g >= NG) return;
  int run = 0;
  for (int b = 0; b < NBUCK; b++) {
    int c = bucketCnt[g * NBUCK + b];
    bucketBase[g * NBUCK + b] = run;
    cursor[g * NBUCK + b] = run;
    run += c;
  }
  rp[g * (NN + 1) + NN] = NE;
}

__global__ __launch_bounds__(256) void bin_kernel(const int* __restrict__ e0,
    const int* __restrict__ e1, const int* __restrict__ e2,
    int* __restrict__ cursor, unsigned int* __restrict__ binned) {
  __shared__ int cnt[NBUCK];
  __shared__ int base[NBUCK];
  int g = blockIdx.y;
  const int* ei = (g == 0) ? e0 : ((g == 1) ? e1 : e2);
  int tid = threadIdx.x;
  if (tid < NBUCK) cnt[tid] = 0;
  __syncthreads();
  int estart = blockIdx.x * EPB_BIN;
  int src[EPT_BIN], dst[EPT_BIN], rk[EPT_BIN];
#pragma unroll
  for (int i = 0; i < EPT_BIN; i++) {
    int e = estart + tid + i * 256;
    if (e < NE) {
      src[i] = ei[e];
      dst[i] = ei[NE + e];
      rk[i] = atomicAdd(&cnt[dst[i] >> 10], 1);
    } else {
      rk[i] = -1;
    }
  }
  __syncthreads();
  if (tid < NBUCK) base[tid] = (cnt[tid] > 0) ? atomicAdd(&cursor[g * NBUCK + tid], cnt[tid]) : 0;
  __syncthreads();
#pragma unroll
  for (int i = 0; i < EPT_BIN; i++) {
    if (rk[i] >= 0) {
      int b = dst[i] >> 10;
      binned[(size_t)g * NE + base[b] + rk[i]] =
          (unsigned int)src[i] | ((unsigned int)dst[i] << 16);
    }
  }
}

// phase 1: per-bucket degree histogram -> rp (global row ptr) + dinv
__global__ __launch_bounds__(256) void csr_kernel(const unsigned int* __restrict__ binned,
    const int* __restrict__ bucketBase, const int* __restrict__ bucketCnt,
    int* __restrict__ rp, float* __restrict__ dinv) {
  __shared__ int deg[BW];
  __shared__ int wsum[4];
  int g = blockIdx.y, b = blockIdx.x;
  int tid = threadIdx.x;
  int node0 = b * BW;
  int bb = bucketBase[g * NBUCK + b];
  int total = bucketCnt[g * NBUCK + b];
  const unsigned int* bp = binned + (size_t)g * NE + bb;
  for (int i = tid; i < BW; i += 256) deg[i] = 0;
  __syncthreads();
  for (int e = tid; e < total; e += 256) {
    unsigned int p = bp[e];
    atomicAdd(&deg[(int)(p >> 16) - node0], 1);
  }
  __syncthreads();
  int d0 = deg[tid * 4], d1 = deg[tid * 4 + 1], d2 = deg[tid * 4 + 2], d3 = deg[tid * 4 + 3];
  int s = d0 + d1 + d2 + d3;
  int lane = tid & 63;
  int incl = s;
#pragma unroll
  for (int off = 1; off < 64; off <<= 1) {
    int n = __shfl_up(incl, off, 64);
    if (lane >= off) incl += n;
  }
  if (lane == 63) wsum[tid >> 6] = incl;
  __syncthreads();
  int wbase = 0;
#pragma unroll
  for (int w = 0; w < 4; w++)
    if (w < (tid >> 6)) wbase += wsum[w];
  int ex = wbase + incl - s;
  int exs[4] = {ex, ex + d0, ex + d0 + d1, ex + d0 + d1 + d2};
  int ds[4] = {d0, d1, d2, d3};
#pragma unroll
  for (int k = 0; k < 4; k++) {
    int node = node0 + tid * 4 + k;
    if (node < NN) {
      rp[g * (NN + 1) + node] = bb + exs[k];
      dinv[g * NN + node] = rsqrtf((float)ds[k] + 1.0f);   // deg incl. self loop
    }
  }
}

// phase 2: scatter packed (src | fp16(dinv[src])) into bucket-private col region
__global__ __launch_bounds__(256) void fillp_kernel(const unsigned int* __restrict__ binned,
    const int* __restrict__ bucketBase, const int* __restrict__ bucketCnt,
    const int* __restrict__ rp, const float* __restrict__ dinv,
    unsigned int* __restrict__ colp) {
  __shared__ int cur[BW];
  int g = blockIdx.y, b = blockIdx.x;
  int tid = threadIdx.x;
  int node0 = b * BW;
  int bb = bucketBase[g * NBUCK + b];
  int total = bucketCnt[g * NBUCK + b];
  const unsigned int* bp = binned + (size_t)g * NE + bb;
  for (int i = tid; i < BW; i += 256) {
    int node = node0 + i;
    cur[i] = (node < NN) ? rp[g * (NN + 1) + node] : 0;
  }
  __syncthreads();
  for (int e = tid; e < total; e += 256) {
    unsigned int p = bp[e];
    int srcid = (int)(p & 0xffffu);
    int r = atomicAdd(&cur[(int)(p >> 16) - node0], 1);
    colp[(size_t)g * NE + r] = packsw(srcid, dinv[g * NN + srcid]);
  }
}

// ---------------- fused 3-branch aggregation: 2 edges per wave-inst ----------------
// lanes 0-31 even slots, lanes 32-63 odd slots; each lane covers 4 features (half4).
// tout[b][w] = dinv_b[i]*( dinv_b[i]*src[i] + sum_e w_e*src[s_e] ), w_e packed fp16.

__global__ __launch_bounds__(256) void aggf_kernel(
    const __half* __restrict__ srch, const int* __restrict__ rp,
    const unsigned int* __restrict__ colp, const float* __restrict__ dinv,
    const int* __restrict__ index, __half* __restrict__ tout, int nrows) {
  int w = (blockIdx.x * 256 + threadIdx.x) >> 6;
  if (w >= nrows) return;
  int lane = threadIdx.x & 63;
  int sub = lane >> 5;           // which edge of the pair this half-wave handles
  int fl = lane & 31;            // feature group: features fl*4 .. fl*4+3
  int node = index ? index[w] : w;
  const _Float16* srcv = (const _Float16*)srch;
  half4v selfh = *(const half4v*)&srcv[(size_t)node * D + fl * 4];
  float di0 = dinv[node], di1 = dinv[NN + node], di2 = dinv[2 * NN + node];
  float a0[4], a1[4], a2[4];
#pragma unroll
  for (int k = 0; k < 4; k++) {
    float sv = sub ? 0.f : (float)selfh[k];
    a0[k] = di0 * sv; a1[k] = di1 * sv; a2[k] = di2 * sv;
  }
  int s0 = rp[node],                e0 = rp[node + 1];
  int s1 = rp[(NN + 1) + node],     e1 = rp[(NN + 1) + node + 1];
  int s2 = rp[2 * (NN + 1) + node], e2 = rp[2 * (NN + 1) + node + 1];
  int n0 = e0 - s0, n1 = e1 - s1, n2 = e2 - s2;
  // packed col regs; lanes beyond degree hold 0 (src 0, weight +0.0) -> no inner bounds checks
  unsigned int c0 = (lane < n0) ? colp[s0 + lane] : 0u;
  unsigned int c1 = (lane < n1) ? colp[NE + s1 + lane] : 0u;
  unsigned int c2 = (lane < n2) ? colp[2 * NE + s2 + lane] : 0u;
  int m0 = min(n0, 64), m1 = min(n1, 64), m2 = min(n2, 64);
  int mx = max(m0, max(m1, m2));
  for (int j = 0; j < mx; j += 8) {
    half4v h0[4], h1[4], h2[4];
    float w0[4], w1[4], w2[4];
    bool p0 = j < m0, p1 = j < m1, p2 = j < m2;   // wave-uniform
    if (p0) {
#pragma unroll
      for (int u = 0; u < 4; u++) {
        unsigned int v = (unsigned int)__shfl((int)c0, j + u * 2 + sub, 64);
        w0[u] = wextract(v);
        h0[u] = *(const half4v*)&srcv[(size_t)(v & 0xffffu) * D + fl * 4];
      }
    }
    if (p1) {
#pragma unroll
      for (int u = 0; u < 4; u++) {
        unsigned int v = (unsigned int)__shfl((int)c1, j + u * 2 + sub, 64);
        w1[u] = wextract(v);
        h1[u] = *(const half4v*)&srcv[(size_t)(v & 0xffffu) * D + fl * 4];
      }
    }
    if (p2) {
#pragma unroll
      for (int u = 0; u < 4; u++) {
        unsigned int v = (unsigned int)__shfl((int)c2, j + u * 2 + sub, 64);
        w2[u] = wextract(v);
        h2[u] = *(const half4v*)&srcv[(size_t)(v & 0xffffu) * D + fl * 4];
      }
    }
    if (p0) {
#pragma unroll
      for (int u = 0; u < 4; u++)
#pragma unroll
        for (int k = 0; k < 4; k++) a0[k] = fmaf((float)h0[u][k], w0[u], a0[k]);
    }
    if (p1) {
#pragma unroll
      for (int u = 0; u < 4; u++)
#pragma unroll
        for (int k = 0; k < 4; k++) a1[k] = fmaf((float)h1[u][k], w1[u], a1[k]);
    }
    if (p2) {
#pragma unroll
      for (int u = 0; u < 4; u++)
#pragma unroll
        for (int k = 0; k < 4; k++) a2[k] = fmaf((float)h2[u][k], w2[u], a2[k]);
    }
  }
  // rare tails (deg > 64)
  for (int q = s0 + 64; q < e0; q += 64) {
    int nn = min(e0 - q, 64);
    unsigned int c = (lane < nn) ? colp[q + lane] : 0u;
    for (int j = 0; j < nn; j += 2) {
      unsigned int v = (unsigned int)__shfl((int)c, j + sub, 64);
      float wf = wextract(v);
      half4v hv = *(const half4v*)&srcv[(size_t)(v & 0xffffu) * D + fl * 4];
#pragma unroll
      for (int k = 0; k < 4; k++) a0[k] = fmaf((float)hv[k], wf, a0[k]);
    }
  }
  for (int q = s1 + 64; q < e1; q += 64) {
    int nn = min(e1 - q, 64);
    unsigned int c = (lane < nn) ? colp[NE + q + lane] : 0u;
    for (int j = 0; j < nn; j += 2) {
      unsigned int v = (unsigned int)__shfl((int)c, j + sub, 64);
      float wf = wextract(v);
      half4v hv = *(const half4v*)&srcv[(size_t)(v & 0xffffu) * D + fl * 4];
#pragma unroll
      for (int k = 0; k < 4; k++) a1[k] = fmaf((float)hv[k], wf, a1[k]);
    }
  }
  for (int q = s2 + 64; q < e2; q += 64) {
    int nn = min(e2 - q, 64);
    unsigned int c = (lane < nn) ? colp[2 * NE + q + lane] : 0u;
    for (int j = 0; j < nn; j += 2) {
      unsigned int v = (unsigned int)__shfl((int)c, j + sub, 64);
      float wf = wextract(v);
      half4v hv = *(const half4v*)&srcv[(size_t)(v & 0xffffu) * D + fl * 4];
#pragma unroll
      for (int k = 0; k < 4; k++) a2[k] = fmaf((float)hv[k], wf, a2[k]);
    }
  }
  // combine the two half-wave partial sums
#pragma unroll
  for (int k = 0; k < 4; k++) {
    a0[k] += __shfl_xor(a0[k], 32, 64);
    a1[k] += __shfl_xor(a1[k], 32, 64);
    a2[k] += __shfl_xor(a2[k], 32, 64);
  }
  if (sub == 0) {
    size_t stride = (size_t)nrows * D;
    _Float16* tv = (_Float16*)tout;
    half4v o0, o1, o2;
#pragma unroll
    for (int k = 0; k < 4; k++) {
      o0[k] = (_Float16)(di0 * a0[k]);
      o1[k] = (_Float16)(di1 * a1[k]);
      o2[k] = (_Float16)(di2 * a2[k]);
    }
    *(half4v*)&tv[(size_t)w * D + fl * 4]              = o0;
    *(half4v*)&tv[stride + (size_t)w * D + fl * 4]     = o1;
    *(half4v*)&tv[2 * stride + (size_t)w * D + fl * 4] = o2;
  }
}

// ---------------- fused 3-branch MFMA fp16 matmul + bias + relu + max ----------------

__global__ __launch_bounds__(256) void mmf_kernel(const __half* __restrict__ A,
    const __half* __restrict__ Wf,
    const float* __restrict__ B0, const float* __restrict__ B1, const float* __restrict__ B2,
    __half* __restrict__ outh, float* __restrict__ outf, int M) {
  __shared__ _Float16 Ws[16384];      // 32 frags x 64 lanes x 8 halves = 32 KB
  const float* Bb[3] = {B0, B1, B2};
  const int tid = threadIdx.x;
  const int wave = tid >> 6, lane = tid & 63;
  const int wr = (wave >> 1) * 64, wc = (wave & 1) * 64;
  const int ln = lane & 15, quad = lane >> 4;
  const int row_base = blockIdx.x * 128 + wr;
  float om[4][4][4];

  for (int b = 0; b < 3; b++) {
    const __half* Wb = Wf + (size_t)b * 16384;
#pragma unroll
    for (int i = 0; i < 8; i++) {
      int id = tid + i * 256;
      *(half8*)&Ws[id * 8] = *(const half8*)&Wb[(size_t)id * 8];
    }
    __syncthreads();

    const __half* Ab = A + (size_t)b * M * D;
    float bias[4];
#pragma unroll
    for (int ct = 0; ct < 4; ct++) bias[ct] = Bb[b][wc + ct * 16 + ln];
    floatx4 acc[4][4];
#pragma unroll
    for (int rt = 0; rt < 4; rt++)
#pragma unroll
      for (int ct = 0; ct < 4; ct++)
        acc[rt][ct] = (floatx4){bias[ct], bias[ct], bias[ct], bias[ct]};

#pragma unroll
    for (int ks = 0; ks < 4; ks++) {
      half8 av[4];
#pragma unroll
      for (int rt = 0; rt < 4; rt++) {
        int r = row_base + rt * 16 + ln;
        r = (r < M) ? r : (M - 1);
        av[rt] = *(const half8*)&Ab[(size_t)r * D + ks * 32 + quad * 8];
      }
#pragma unroll
      for (int ct = 0; ct < 4; ct++) {
        int tt = (wc >> 4) + ct;
        half8 bv = *(const half8*)&Ws[((tt * 4 + ks) * 64 + lane) * 8];
#pragma unroll
        for (int rt = 0; rt < 4; rt++)
          acc[rt][ct] = __builtin_amdgcn_mfma_f32_16x16x32_f16(av[rt], bv, acc[rt][ct], 0, 0, 0);
      }
    }
#pragma unroll
    for (int rt = 0; rt < 4; rt++)
#pragma unroll
      for (int ct = 0; ct < 4; ct++)
#pragma unroll
        for (int r = 0; r < 4; r++) {
          float v = fmaxf(acc[rt][ct][r], 0.f);
          om[rt][ct][r] = (b == 0) ? v : fmaxf(om[rt][ct][r], v);
        }
    __syncthreads();
  }
#pragma unroll
  for (int rt = 0; rt < 4; rt++) {
    int m = row_base + rt * 16 + quad * 4;
#pragma unroll
    for (int r = 0; r < 4; r++) {
      if (m + r < M) {
#pragma unroll
        for (int ct = 0; ct < 4; ct++) {
          int n = wc + ct * 16 + ln;
          if (outh) outh[(size_t)(m + r) * D + n] = __float2half(om[rt][ct][r]);
          else      outf[(size_t)(m + r) * D + n] = om[rt][ct][r];
        }
      }
    }
  }
}

// ---------------- launch ----------------

extern "C" void kernel_launch(void* const* d_in, const int* in_sizes, int n_in,
                              void* d_out, int out_size, void* d_ws, size_t ws_size,
                              hipStream_t stream) {
  const float* x = (const float*)d_in[0];
  const int* e0 = (const int*)d_in[1];
  const int* e1 = (const int*)d_in[2];
  const int* e2 = (const int*)d_in[3];
  const int* index = (const int*)d_in[4];
  const float* w1[3] = {(const float*)d_in[5], (const float*)d_in[9],  (const float*)d_in[13]};
  const float* b1[3] = {(const float*)d_in[6], (const float*)d_in[10], (const float*)d_in[14]};
  const float* w2[3] = {(const float*)d_in[7], (const float*)d_in[11], (const float*)d_in[15]};
  const float* b2[3] = {(const float*)d_in[8], (const float*)d_in[12], (const float*)d_in[16]};
  float* out = (float*)d_out;

  char* ws = (char*)d_ws;
  size_t o = 0;
  auto alloc = [&](size_t bytes) {
    o = (o + 255) & ~(size_t)255;
    void* p = ws + o;
    o += bytes;
    return p;
  };
  int*    rp     = (int*)alloc((size_t)NG * (NN + 1) * 4);
  unsigned int* colp = (unsigned int*)alloc((size_t)NG * NE * 4);
  float*  dinv   = (float*)alloc((size_t)NG * NN * 4);
  int*    bcnt   = (int*)alloc((size_t)NG * NBUCK * 4);
  int*    bbase  = (int*)alloc((size_t)NG * NBUCK * 4);
  int*    bcur   = (int*)alloc((size_t)NG * NBUCK * 4);
  __half* xh     = (__half*)alloc((size_t)NN * D * 2);        // 12.8 MB
  __half* Wf     = (__half*)alloc((size_t)6 * 128 * 128 * 2); // 196 KB
  __half* t1     = (__half*)alloc((size_t)NG * NN * D * 2);   // 38.4 MB
  __half* hacc   = (__half*)alloc((size_t)NN * D * 2);        // 12.8 MB
  unsigned int* binned = (unsigned int*)t1;  // alias: consumed by csr/fillp before aggf writes t1
  __half* t2     = t1;                       // alias: t1 free during layer 2
  (void)ws_size; (void)in_sizes; (void)n_in; (void)out_size;

  hipMemsetAsync(bcnt, 0, (size_t)NG * NBUCK * 4, stream);
  xcvt_kernel<<<(NN * D / 2 + 255) / 256, 256, 0, stream>>>(x, xh, NN * D / 2);
  wcvt_kernel<<<48, 256, 0, stream>>>(w1[0], w1[1], w1[2], w2[0], w2[1], w2[2], Wf);
  count_kernel<<<dim3(NBLK_BIN, NG), 256, 0, stream>>>(e0, e1, e2, bcnt);
  bscan_kernel<<<1, 64, 0, stream>>>(bcnt, bbase, bcur, rp);
  bin_kernel<<<dim3(NBLK_BIN, NG), 256, 0, stream>>>(e0, e1, e2, bcur, binned);
  csr_kernel<<<dim3(NBUCK, NG), 256, 0, stream>>>(binned, bbase, bcnt, rp, dinv);
  fillp_kernel<<<dim3(NBUCK, NG), 256, 0, stream>>>(binned, bbase, bcnt, rp, dinv, colp);

  // layer 1: t1_b = Norm_b(xh);  hacc = max_b relu(t1_b @ W1_b + b1_b)   [fp16]
  aggf_kernel<<<(NN * 64 + 255) / 256, 256, 0, stream>>>(xh, rp, colp, dinv, nullptr, t1, NN);
  mmf_kernel<<<(NN + 127) / 128, 256, 0, stream>>>(t1, Wf, b1[0], b1[1], b1[2],
                                                   hacc, nullptr, NN);
  // layer 2: t2_b = Norm_b(hacc)[index];  out = max_b relu(t2_b @ W2_b + b2_b)
  aggf_kernel<<<(NI * 64 + 255) / 256, 256, 0, stream>>>(hacc, rp, colp, dinv, index, t2, NI);
  mmf_kernel<<<(NI + 127) / 128, 256, 0, stream>>>(t2, Wf + (size_t)3 * 16384,
                                                   b2[0], b2[1], b2[2], nullptr, out, NI);
}